// Round 10
// baseline (44.965 us; speedup 1.0000x reference)
//
#include <hip/hip_runtime.h>
#include <cstdint>
#include <cfloat>
#include <cstddef>

#define BB 8
#define VV 2048
#define SS 4
#define FF 64
#define KK 8

// Largest f32 that stays FINITE when rounded to bf16 (FLT_MAX -> bf16 = +inf).
#define BF16_SAFE_MAX 3.3e38f

typedef unsigned long long u64;
typedef unsigned int u32;

// u32 compare-exchange: 2 instrs (min+max), no payload
#define CEU(A, x, y) { u32 lo_ = A[x] < A[y] ? A[x] : A[y];                    \
                       u32 hi_ = A[x] < A[y] ? A[y] : A[x];                    \
                       A[x] = lo_; A[y] = hi_; }
#define CEK(A, x, y) { u64 lo_ = A[x] < A[y] ? A[x] : A[y];                    \
                       u64 hi_ = A[x] < A[y] ? A[y] : A[x];                    \
                       A[x] = lo_; A[y] = hi_; }

// Batcher odd-even mergesort, n=8, 19 comparators
#define SORT8_32(K)                                                            \
    CEU(K,0,1) CEU(K,2,3) CEU(K,4,5) CEU(K,6,7)                                \
    CEU(K,0,2) CEU(K,1,3) CEU(K,4,6) CEU(K,5,7)                                \
    CEU(K,1,2) CEU(K,5,6)                                                      \
    CEU(K,0,4) CEU(K,1,5) CEU(K,2,6) CEU(K,3,7)                                \
    CEU(K,2,4) CEU(K,3,5)                                                      \
    CEU(K,1,2) CEU(K,3,4) CEU(K,5,6)

#define SORT8_64(K)                                                            \
    CEK(K,0,1) CEK(K,2,3) CEK(K,4,5) CEK(K,6,7)                                \
    CEK(K,0,2) CEK(K,1,3) CEK(K,4,6) CEK(K,5,7)                                \
    CEK(K,1,2) CEK(K,5,6)                                                      \
    CEK(K,0,4) CEK(K,1,5) CEK(K,2,6) CEK(K,3,7)                                \
    CEK(K,2,4) CEK(K,3,5)                                                      \
    CEK(K,1,2) CEK(K,3,4) CEK(K,5,6)

// keep 8 smallest u32 values of sorted T(8) + sorted Bk(8)
#define MERGE8_32(T, Bk) {                                                     \
    u32 t[KK];                                                                 \
    t[0] = T[0] < Bk[7] ? T[0] : Bk[7];                                        \
    t[1] = T[1] < Bk[6] ? T[1] : Bk[6];                                        \
    t[2] = T[2] < Bk[5] ? T[2] : Bk[5];                                        \
    t[3] = T[3] < Bk[4] ? T[3] : Bk[4];                                        \
    t[4] = T[4] < Bk[3] ? T[4] : Bk[3];                                        \
    t[5] = T[5] < Bk[2] ? T[5] : Bk[2];                                        \
    t[6] = T[6] < Bk[1] ? T[6] : Bk[1];                                        \
    t[7] = T[7] < Bk[0] ? T[7] : Bk[0];                                        \
    CEU(t,0,4) CEU(t,1,5) CEU(t,2,6) CEU(t,3,7)                                \
    CEU(t,0,2) CEU(t,1,3) CEU(t,4,6) CEU(t,5,7)                                \
    CEU(t,0,1) CEU(t,2,3) CEU(t,4,5) CEU(t,6,7)                                \
    T[0]=t[0]; T[1]=t[1]; T[2]=t[2]; T[3]=t[3];                                \
    T[4]=t[4]; T[5]=t[5]; T[6]=t[6]; T[7]=t[7]; }

// 32 lanes per row, 2 rows/wave, 8 strided rows/block. One 40KB LDS window.
// Scan on u32 dist-bits (cached in 64 VGPRs); exact (dist,idx) order recovered
// via a single ballot pass + per-row strict/tie lists + one u64 SORT8.
__global__ __launch_bounds__(256, 4)
void knn_topk_kernel(const float* __restrict__ coords,   // [B,V,S] f32
                     const float* __restrict__ feats,    // [B,V,F] f32
                     const float* __restrict__ active,   // [B,1]   f32
                     float* __restrict__ out_dist,       // [B,V,K-1]
                     float* __restrict__ out_feat)       // [B,V,K-1,F]
{
#pragma clang fp contract(off)
    __shared__ float4 sc[VV];   // 32 KB
    __shared__ float  sn[VV];   //  8 KB (first 1 KB re-used as key lists later)

    const int b    = blockIdx.x;           // batch -> XCD (linear id % 8 == b)
    const int bx   = blockIdx.y;
    const int tid  = threadIdx.x;
    const int l    = tid & 31;             // lane within 32-lane row-group
    const int j    = tid >> 5;             // row slot 0..7
    const int v    = bx + (j << 8);        // strided rows: perfect balance
    const int gb32 = tid & 32;             // group base within wave (0 or 32)

    const float A = active[b];
    int Ai = (int)ceilf(A);
    Ai = Ai < 0 ? 0 : (Ai > VV ? VV : Ai);

    const size_t row = (size_t)b * VV + v;
    const float4* cg = reinterpret_cast<const float4*>(coords + (size_t)b * VV * SS);

    const bool rowActive = ((float)v < A);
    const bool heavy = (__ballot(rowActive) != 0ULL);   // wave-uniform
    const float Aeff = rowActive ? A : -1.0f;           // folds row mask into w-mask

    const float4 cv = cg[v];
    float qp0 = cv.x*cv.x, qp1 = cv.y*cv.y, qp2 = cv.z*cv.z, qp3 = cv.w*cv.w;
    const float nv = ((qp0 + qp1) + qp2) + qp3;
    const float lf = (float)l;

    int nt = (Ai + 31) >> 5;               // candidate tiles (32 wide)
    if (nt < 8) nt = 8;                    // >= 8 keys per lane
    const int nb = (nt + 7) >> 3;          // batches of 8 tiles, 1..8

    // ---- stage all candidates (coords + norms) ----
    for (int i = tid; i < VV; i += 256) {
        const float4 c = cg[i];
        sc[i] = c;
        float p0 = c.x*c.x, p1 = c.y*c.y, p2 = c.z*c.z, p3 = c.w*c.w;
        sn[i] = ((p0 + p1) + p2) + p3;     // np-style sequential reduce
    }
    __syncthreads();

    float dreg[64];                        // cached dists, statically indexed
    u32 top[KK];
#pragma unroll
    for (int i = 0; i < KK; ++i) top[i] = 0xFFFFFFFFu;

    if (heavy) {
#pragma unroll
        for (int bt = 0; bt < 8; ++bt) if (bt < nb) {
            u32 bk[KK];
#pragma unroll
            for (int kk = 0; kk < 8; ++kk) {
                const int k = (bt << 3) + kk;
                const int wb = k << 5;
                const float4 cw = sc[wb + l];     // static byte offset per k
                const float  nw = sn[wb + l];
                float p0 = cv.x*cw.x, p1 = cv.y*cw.y,
                      p2 = cv.z*cw.z, p3 = cv.w*cw.w;
                float dot = ((p0 + p1) + p2) + p3;
                float sd = -2.0f * dot;
                sd = sd + nv;
                sd = sd + nw;
                sd = fabsf(sd);
                const float fw = lf + (float)wb;  // exact: both < 2048
                const float dvf = (fw < Aeff) ? sd : FLT_MAX;
                dreg[k] = dvf;
                bk[kk] = __float_as_uint(dvf);
            }
            SORT8_32(bk)
            MERGE8_32(top, bk)
        }
    }

    __syncthreads();   // all sn reads done block-wide; sb alias now safe

    // ---- trivial rows: top-8 of all-FLT_MAX row = indices 0..7 ----
    if (!heavy) {
        if (l >= 1 && l < KK)
            out_dist[row * (KK - 1) + (l - 1)] = BF16_SAFE_MAX;
#pragma unroll
        for (int r = 1; r < KK; ++r) {
            const float2 val = reinterpret_cast<const float2*>(
                feats + ((size_t)b * VV + r) * FF)[l];
            reinterpret_cast<float2*>(out_feat + (row * (KK - 1) + (r - 1)) * FF)[l] = val;
        }
        return;
    }

    // ---- cross-lane merge of u32 dist VALUES (5 levels) -> exact 8th value ----
#pragma unroll
    for (int step = 1; step < 32; step <<= 1) {
        u32 t[KK];
#pragma unroll
        for (int i = 0; i < KK; ++i) {
            u32 pb = (u32)__shfl_xor((int)top[KK - 1 - i], step, 64);
            u32 a0 = top[i];
            t[i] = a0 < pb ? a0 : pb;
        }
        CEU(t,0,4) CEU(t,1,5) CEU(t,2,6) CEU(t,3,7)
        CEU(t,0,2) CEU(t,1,3) CEU(t,4,6) CEU(t,5,7)
        CEU(t,0,1) CEU(t,2,3) CEU(t,4,5) CEU(t,6,7)
#pragma unroll
        for (int i = 0; i < KK; ++i) top[i] = t[i];
    }
    const float tauf = __uint_as_float(top[KK - 1]);   // row's 8th-smallest dist

    // ---- index recovery from the register cache (single pass, no re-compute) ----
    // strict hits (d < tau): <= 7 per row, all belong to top-8.
    // ties (d == tau): lowest-w fill the remaining slots = reference tie-break.
    u64* sb = reinterpret_cast<u64*>(sn);   // [8 rows][16 slots]: A=0..7, B=8..15
    const u32 lbelow = (1u << l) - 1u;
    u32 cntA = 0, cntB = 0;
#pragma unroll
    for (int bt = 0; bt < 8; ++bt) if (bt < nb) {
#pragma unroll
        for (int kk = 0; kk < 8; ++kk) {
            const int k = (bt << 3) + kk;
            const float d = dreg[k];
            const bool ps = (d < tauf);
            const bool pt = (d == tauf);
            const u64 bs = __ballot(ps);
            const u64 bq = __ballot(pt);
            const u32 msS = gb32 ? (u32)(bs >> 32) : (u32)bs;
            const u32 msT = gb32 ? (u32)(bq >> 32) : (u32)bq;
            if (ps) {
                const u32 s = cntA + (u32)__popc(msS & lbelow);
                if (s < 8) sb[(j << 4) + s] =
                    ((u64)__float_as_uint(d) << 32) | (u32)((k << 5) + l);
            } else if (pt) {
                const u32 s = cntB + (u32)__popc(msT & lbelow);
                if (s < 8) sb[(j << 4) + 8 + s] =
                    ((u64)__float_as_uint(d) << 32) | (u32)((k << 5) + l);
            }
            cntA += (u32)__popc(msS);
            cntB += (u32)__popc(msT);
        }
    }

    // ---- assemble 8 keys (all strict + first ties), sort once by (d,w) ----
    u64 key[KK];
#pragma unroll
    for (int r = 0; r < KK; ++r) {
        const int idx = (r < (int)cntA) ? r : (8 + r - (int)cntA);
        key[r] = sb[(j << 4) + idx];       // runtime LDS index: fine
    }
    SORT8_64(key)
    // key[0..7] = row's exact top-8 ascending by (dist, idx); rank 0 = self

    // ---- epilogue ----
    u32 kd = 0;
#pragma unroll
    for (int r = 1; r < KK; ++r) kd = (l == r) ? (u32)(key[r] >> 32) : kd;
    if (l >= 1 && l < KK) {
        float d = __uint_as_float(kd);
        if (!(d <= BF16_SAFE_MAX)) d = BF16_SAFE_MAX;  // finite in bf16; kills NaN
        out_dist[row * (KK - 1) + (l - 1)] = d;
    }

#pragma unroll
    for (int r = 1; r < KK; ++r) {
        const u32 idx = (u32)key[r] & (VV - 1);
        const float2 val = reinterpret_cast<const float2*>(
            feats + ((size_t)b * VV + idx) * FF)[l];
        reinterpret_cast<float2*>(out_feat + (row * (KK - 1) + (r - 1)) * FF)[l] = val;
    }
}

extern "C" void kernel_launch(void* const* d_in, const int* in_sizes, int n_in,
                              void* d_out, int out_size, void* d_ws, size_t ws_size,
                              hipStream_t stream)
{
    const float* coords = (const float*)d_in[0];
    const float* feats  = (const float*)d_in[1];
    const float* act    = (const float*)d_in[2];
    float* out_dist = (float*)d_out;
    float* out_feat = out_dist + (size_t)BB * VV * (KK - 1);

    // grid.x = batch so each batch's 256 blocks land on one XCD (L2 locality
    // for that batch's 4 MB feats slice): linear id % 8 == blockIdx.x == b.
    dim3 grid(BB, VV / 8);
    knn_topk_kernel<<<grid, dim3(256), 0, stream>>>(coords, feats, act,
                                                    out_dist, out_feat);
}

// Round 11
// 31.778 us; speedup vs baseline: 1.4150x; 1.4150x over previous
//
#include <hip/hip_runtime.h>
#include <cstdint>
#include <cfloat>
#include <cstddef>

#define BB 8
#define VV 2048
#define SS 4
#define FF 64
#define KK 8

// Largest f32 that stays FINITE when rounded to bf16 (FLT_MAX -> bf16 = +inf).
#define BF16_SAFE_MAX 3.3e38f

typedef unsigned long long u64;
typedef unsigned int u32;

// ---- f64-packed keys: value order == (dist_bits, index) lexicographic ----
// bits = (1<<62) | (dist_bits << 20) | w  -> normal positive double, never NaN/inf.
// fmin/fmax = v_min_f64/v_max_f64: a 2-instruction compare-exchange with the
// index embedded (vs 5-instr u64 cmp+cndmask chain).
#define KEY_BIAS (1ULL << 62)

static __forceinline__ __device__ double mk_key(float d, u32 w) {
    return __longlong_as_double(
        (long long)(KEY_BIAS | ((u64)__float_as_uint(d) << 20) | (u64)w));
}
static __forceinline__ __device__ u32 key_dist(double k) {
    return (u32)(((u64)__double_as_longlong(k)) >> 20);   // low 32 of shift: dist bits
}
static __forceinline__ __device__ u32 key_idx(double k) {
    return (u32)((u64)__double_as_longlong(k) & (u64)(VV - 1));
}
static __forceinline__ __device__ double shfl_xor_f64(double x, int m) {
    const u64 b = (u64)__double_as_longlong(x);
    int lo = __shfl_xor((int)(u32)b, m, 64);
    int hi = __shfl_xor((int)(u32)(b >> 32), m, 64);
    return __longlong_as_double((long long)(((u64)(u32)hi << 32) | (u32)lo));
}

#define CED(A, x, y) { double lo_ = fmin(A[x], A[y]);                          \
                       double hi_ = fmax(A[x], A[y]);                          \
                       A[x] = lo_; A[y] = hi_; }

// Batcher odd-even mergesort, n=8, 19 comparators (2 instr each)
#define SORT8D(K)                                                              \
    CED(K,0,1) CED(K,2,3) CED(K,4,5) CED(K,6,7)                                \
    CED(K,0,2) CED(K,1,3) CED(K,4,6) CED(K,5,7)                                \
    CED(K,1,2) CED(K,5,6)                                                      \
    CED(K,0,4) CED(K,1,5) CED(K,2,6) CED(K,3,7)                                \
    CED(K,2,4) CED(K,3,5)                                                      \
    CED(K,1,2) CED(K,3,4) CED(K,5,6)

// merge sorted-asc T(8) with sorted-asc Bk(8): keep 8 smallest, sorted, in T
#define MERGE8D(T, Bk) {                                                       \
    double t[KK];                                                              \
    t[0] = fmin(T[0], Bk[7]);                                                  \
    t[1] = fmin(T[1], Bk[6]);                                                  \
    t[2] = fmin(T[2], Bk[5]);                                                  \
    t[3] = fmin(T[3], Bk[4]);                                                  \
    t[4] = fmin(T[4], Bk[3]);                                                  \
    t[5] = fmin(T[5], Bk[2]);                                                  \
    t[6] = fmin(T[6], Bk[1]);                                                  \
    t[7] = fmin(T[7], Bk[0]);                                                  \
    CED(t,0,4) CED(t,1,5) CED(t,2,6) CED(t,3,7)                                \
    CED(t,0,2) CED(t,1,3) CED(t,4,6) CED(t,5,7)                                \
    CED(t,0,1) CED(t,2,3) CED(t,4,5) CED(t,6,7)                                \
    T[0]=t[0]; T[1]=t[1]; T[2]=t[2]; T[3]=t[3];                                \
    T[4]=t[4]; T[5]=t[5]; T[6]=t[6]; T[7]=t[7]; }

// 32 lanes per query row, 2 rows per wave, 8 strided rows per block.
// LDS 20480 B = 160KB/8; VGPR<=64 -> 8 blocks/CU; grid = 2048 = one full round.
__global__ __launch_bounds__(256, 8)
void knn_topk_kernel(const float* __restrict__ coords,   // [B,V,S] f32
                     const float* __restrict__ feats,    // [B,V,F] f32
                     const float* __restrict__ active,   // [B,1]   f32
                     float* __restrict__ out_dist,       // [B,V,K-1]
                     float* __restrict__ out_feat)       // [B,V,K-1,F]
{
#pragma clang fp contract(off)
    __shared__ float4 sc[VV / 2];   // 16 KB (one half-range of candidates)
    __shared__ float  sn[VV / 2];   //  4 KB

    const int b   = blockIdx.y;
    const int tid = threadIdx.x;
    const int l   = tid & 31;              // lane within 32-lane row-group
    const int j   = tid >> 5;              // row slot 0..7
    const int v   = blockIdx.x + (j << 8); // strided rows: perfect balance

    const float A = active[b];
    int Ai = (int)ceilf(A);
    Ai = Ai < 0 ? 0 : (Ai > VV ? VV : Ai);

    const size_t row = (size_t)b * VV + v;
    const float4* cg = reinterpret_cast<const float4*>(coords + (size_t)b * VV * SS);

    const bool rowActive = ((float)v < A);
    const bool heavy = (__ballot(rowActive) != 0ULL);   // wave-uniform

    // query coords/norm from global (row may live in either staging pass)
    const float4 cv = cg[v];
    float qp0 = cv.x*cv.x, qp1 = cv.y*cv.y, qp2 = cv.z*cv.z, qp3 = cv.w*cv.w;
    const float nv = ((qp0 + qp1) + qp2) + qp3;

    // running top-8, sorted ascending, f64-packed (dist, idx) keys
    double top[KK];
#pragma unroll
    for (int i = 0; i < KK; ++i)
        top[i] = __longlong_as_double((long long)(KEY_BIAS | 0xFFFFFFFFFFFFFULL));

    const int nfullt      = Ai >> 5;                         // tiles fully < A
    int ntiles_total      = (Ai + 31) >> 5;
    if (ntiles_total < KK) ntiles_total = KK;                // >=8 real keys/lane
    const int nb_total    = (ntiles_total + 7) >> 3;         // batches (8 tiles)
    const int nb1         = nb_total < 4 ? nb_total : 4;     // pass-1 batches

#define STAGE(P)                                                               \
    for (int i = tid; i < VV / 2; i += 256) {                                  \
        const float4 c = cg[i + ((P) << 10)];                                  \
        sc[i] = c;                                                             \
        float p0 = c.x*c.x, p1 = c.y*c.y, p2 = c.z*c.z, p3 = c.w*c.w;          \
        sn[i] = ((p0 + p1) + p2) + p3;                                         \
    }

#define SCAN_BATCH(M)                                                          \
    {                                                                          \
        const int bt = (M) << 3;                                               \
        double bk[KK];                                                         \
        if (bt + 8 <= nfullt) {            /* all w < A (uniform) */           \
            _Pragma("unroll")                                                  \
            for (int k = 0; k < 8; ++k) {                                      \
                const int w  = ((bt + k) << 5) + l;                            \
                const int wi = w & (VV / 2 - 1);                               \
                const float4 cw = sc[wi];                                      \
                const float  nw = sn[wi];                                      \
                float p0 = cv.x*cw.x, p1 = cv.y*cw.y,                          \
                      p2 = cv.z*cw.z, p3 = cv.w*cw.w;                          \
                float dot = ((p0 + p1) + p2) + p3;                             \
                float sd = -2.0f * dot;                                        \
                sd = sd + nv;                                                  \
                sd = sd + nw;                                                  \
                sd = fabsf(sd);                                                \
                const float dvf = rowActive ? sd : FLT_MAX;                    \
                bk[k] = mk_key(dvf, (u32)w);                                   \
            }                                                                  \
        } else {                           /* boundary/pad batch */            \
            _Pragma("unroll")                                                  \
            for (int k = 0; k < 8; ++k) {                                      \
                const int w  = ((bt + k) << 5) + l;                            \
                const int wi = w & (VV / 2 - 1);                               \
                const float4 cw = sc[wi];                                      \
                const float  nw = sn[wi];                                      \
                float p0 = cv.x*cw.x, p1 = cv.y*cw.y,                          \
                      p2 = cv.z*cw.z, p3 = cv.w*cw.w;                          \
                float dot = ((p0 + p1) + p2) + p3;                             \
                float sd = -2.0f * dot;                                        \
                sd = sd + nv;                                                  \
                sd = sd + nw;                                                  \
                sd = fabsf(sd);                                                \
                const bool m = rowActive && ((float)w < A);                    \
                const float dvf = m ? sd : FLT_MAX;                            \
                bk[k] = mk_key(dvf, (u32)w);                                   \
            }                                                                  \
        }                                                                      \
        SORT8D(bk)                                                             \
        MERGE8D(top, bk)                                                       \
    }

    // ---- pass 1: candidates w in [0, 1024) ----
    STAGE(0)
    __syncthreads();
    if (heavy) {
        for (int m = 0; m < nb1; ++m) SCAN_BATCH(m)
    }

    // ---- pass 2: candidates w in [1024, 2048) ----
    if (nb_total > 4) {
        __syncthreads();          // everyone done reading pass-1 LDS
        STAGE(1)
        __syncthreads();
        if (heavy) {
            for (int m = 4; m < nb_total; ++m) SCAN_BATCH(m)
        }
    }
#undef STAGE
#undef SCAN_BATCH

    // ---- trivial rows: top-8 of all-FLT_MAX row = indices 0..7 ----
    if (!heavy) {
        if (l >= 1 && l < KK)
            out_dist[row * (KK - 1) + (l - 1)] = BF16_SAFE_MAX;
#pragma unroll
        for (int r = 1; r < KK; ++r) {
            const float2 val = reinterpret_cast<const float2*>(
                feats + ((size_t)b * VV + r) * FF)[l];
            reinterpret_cast<float2*>(out_feat + (row * (KK - 1) + (r - 1)) * FF)[l] = val;
        }
        return;
    }

    // ---- 5-level truncated bitonic merge across the 32-lane group ----
#pragma unroll
    for (int step = 1; step < 32; step <<= 1) {
        double t[KK];
#pragma unroll
        for (int i = 0; i < KK; ++i) {
            double pb = shfl_xor_f64(top[KK - 1 - i], step);
            t[i] = fmin(top[i], pb);
        }
        CED(t,0,4) CED(t,1,5) CED(t,2,6) CED(t,3,7)
        CED(t,0,2) CED(t,1,3) CED(t,4,6) CED(t,5,7)
        CED(t,0,1) CED(t,2,3) CED(t,4,5) CED(t,6,7)
#pragma unroll
        for (int i = 0; i < KK; ++i) top[i] = t[i];
    }
    // all 32 lanes hold the row's top-8 ascending; rank 0 = self/dropped

    // ---- epilogue ----
    u32 kd = 0;
#pragma unroll
    for (int r = 1; r < KK; ++r) kd = (l == r) ? key_dist(top[r]) : kd;
    if (l >= 1 && l < KK) {
        float d = __uint_as_float(kd);
        if (!(d <= BF16_SAFE_MAX)) d = BF16_SAFE_MAX;  // finite in bf16; kills NaN
        out_dist[row * (KK - 1) + (l - 1)] = d;
    }

#pragma unroll
    for (int r = 1; r < KK; ++r) {
        const u32 idx = key_idx(top[r]);
        const float2 val = reinterpret_cast<const float2*>(
            feats + ((size_t)b * VV + idx) * FF)[l];
        reinterpret_cast<float2*>(out_feat + (row * (KK - 1) + (r - 1)) * FF)[l] = val;
    }
}

extern "C" void kernel_launch(void* const* d_in, const int* in_sizes, int n_in,
                              void* d_out, int out_size, void* d_ws, size_t ws_size,
                              hipStream_t stream)
{
    const float* coords = (const float*)d_in[0];
    const float* feats  = (const float*)d_in[1];
    const float* act    = (const float*)d_in[2];
    float* out_dist = (float*)d_out;
    float* out_feat = out_dist + (size_t)BB * VV * (KK - 1);

    dim3 grid(VV / 8, BB);    // 2048 blocks = 256 CU x 8 blocks/CU: one round
    knn_topk_kernel<<<grid, dim3(256), 0, stream>>>(coords, feats, act,
                                                    out_dist, out_feat);
}

// Round 12
// 28.433 us; speedup vs baseline: 1.5815x; 1.1176x over previous
//
#include <hip/hip_runtime.h>
#include <cstdint>
#include <cfloat>
#include <cstddef>

#define BB 8
#define VV 2048
#define SS 4
#define FF 64
#define KK 8

// Largest f32 that stays FINITE when rounded to bf16 (FLT_MAX -> bf16 = +inf).
#define BF16_SAFE_MAX 3.3e38f

typedef unsigned long long u64;
typedef unsigned int u32;

// ---- f64-packed keys: value order == (dist_bits, index) lexicographic ----
// bits = (1<<62) | (dist_bits << 20) | w  -> normal positive double (exp<=0x47F),
// never NaN/inf; sentinel (1<<62)|0xFFFFFFFFFFFFF is > any real key.
// fmin/fmax (v_min_f64/v_max_f64) = 2-instruction CE with the index embedded.
#define KEY_BIAS (1ULL << 62)

static __forceinline__ __device__ double mk_key(float d, u32 w) {
    return __longlong_as_double(
        (long long)(KEY_BIAS | ((u64)__float_as_uint(d) << 20) | (u64)w));
}
static __forceinline__ __device__ u32 key_dist(double k) {
    return (u32)(((u64)__double_as_longlong(k)) >> 20);
}
static __forceinline__ __device__ u32 key_idx(double k) {
    return (u32)((u64)__double_as_longlong(k) & (u64)(VV - 1));
}
static __forceinline__ __device__ double shfl_xor_f64(double x, int m) {
    const u64 b = (u64)__double_as_longlong(x);
    int lo = __shfl_xor((int)(u32)b, m, 64);
    int hi = __shfl_xor((int)(u32)(b >> 32), m, 64);
    return __longlong_as_double((long long)(((u64)(u32)hi << 32) | (u32)lo));
}

#define CED(A, x, y) { double lo_ = fmin(A[x], A[y]);                          \
                       double hi_ = fmax(A[x], A[y]);                          \
                       A[x] = lo_; A[y] = hi_; }

// Batcher odd-even mergesort, n=8, 19 comparators, on A[base..base+7]
#define SORT8D(K, O)                                                           \
    CED(K,O+0,O+1) CED(K,O+2,O+3) CED(K,O+4,O+5) CED(K,O+6,O+7)                \
    CED(K,O+0,O+2) CED(K,O+1,O+3) CED(K,O+4,O+6) CED(K,O+5,O+7)                \
    CED(K,O+1,O+2) CED(K,O+5,O+6)                                              \
    CED(K,O+0,O+4) CED(K,O+1,O+5) CED(K,O+2,O+6) CED(K,O+3,O+7)                \
    CED(K,O+2,O+4) CED(K,O+3,O+5)                                              \
    CED(K,O+1,O+2) CED(K,O+3,O+4) CED(K,O+5,O+6)

// bitonic clean of t[0..7] (strides 4,2,1)
#define CLEAN8D(t)                                                             \
    CED(t,0,4) CED(t,1,5) CED(t,2,6) CED(t,3,7)                                \
    CED(t,0,2) CED(t,1,3) CED(t,4,6) CED(t,5,7)                                \
    CED(t,0,1) CED(t,2,3) CED(t,4,5) CED(t,6,7)

// merge sorted-asc T(8) with sorted-asc S(8): keep 8 smallest sorted in T
#define MERGE8D(T, S) {                                                        \
    double t[KK];                                                              \
    t[0] = fmin(T[0], S[7]);  t[1] = fmin(T[1], S[6]);                         \
    t[2] = fmin(T[2], S[5]);  t[3] = fmin(T[3], S[4]);                         \
    t[4] = fmin(T[4], S[3]);  t[5] = fmin(T[5], S[2]);                         \
    t[6] = fmin(T[6], S[1]);  t[7] = fmin(T[7], S[0]);                         \
    CLEAN8D(t)                                                                 \
    T[0]=t[0]; T[1]=t[1]; T[2]=t[2]; T[3]=t[3];                                \
    T[4]=t[4]; T[5]=t[5]; T[6]=t[6]; T[7]=t[7]; }

// 32 lanes per query row, 2 rows per wave, 8 strided rows per block.
// LDS 20 KB two-pass staging; batch = 16 tiles with truncated sort16->8.
__global__ __launch_bounds__(256, 6)
void knn_topk_kernel(const float* __restrict__ coords,   // [B,V,S] f32
                     const float* __restrict__ feats,    // [B,V,F] f32
                     const float* __restrict__ active,   // [B,1]   f32
                     float* __restrict__ out_dist,       // [B,V,K-1]
                     float* __restrict__ out_feat)       // [B,V,K-1,F]
{
#pragma clang fp contract(off)
    __shared__ float4 sc[VV / 2];   // 16 KB: holds -2*c for one half-range
    __shared__ float  sn[VV / 2];   //  4 KB: norms of original c

    const int b   = blockIdx.y;
    const int tid = threadIdx.x;
    const int l   = tid & 31;              // lane within 32-lane row-group
    const int j   = tid >> 5;              // row slot 0..7
    const int v   = blockIdx.x + (j << 8); // strided rows: perfect balance

    const float A = active[b];
    int Ai = (int)ceilf(A);
    Ai = Ai < 0 ? 0 : (Ai > VV ? VV : Ai);

    const size_t row = (size_t)b * VV + v;
    const float4* cg = reinterpret_cast<const float4*>(coords + (size_t)b * VV * SS);

    const bool rowActive = ((float)v < A);
    const bool heavy = (__ballot(rowActive) != 0ULL);   // wave-uniform
    const int  Aieff = rowActive ? Ai : 0;              // int mask: w < Aieff

    // query coords/norm from global (row may live in either staging pass)
    const float4 cv = cg[v];
    float qp0 = cv.x*cv.x, qp1 = cv.y*cv.y, qp2 = cv.z*cv.z, qp3 = cv.w*cv.w;
    const float nv = ((qp0 + qp1) + qp2) + qp3;

    // running top-8, sorted ascending, f64-packed (dist, idx) keys
    double top[KK];
#pragma unroll
    for (int i = 0; i < KK; ++i)
        top[i] = __longlong_as_double((long long)(KEY_BIAS | 0xFFFFFFFFFFFFFULL));

    int ntiles = (Ai + 31) >> 5;                 // candidate tiles (32 wide)
    if (ntiles < 16) ntiles = 16;                // >= 16 keys/lane (all real)
    const int nb = (ntiles + 15) >> 4;           // batches of 16 tiles, 1..4
    const int nb1 = nb < 2 ? nb : 2;             // pass-1 batches (w < 1024)

#define STAGE(P)                                                               \
    for (int i = tid; i < VV / 2; i += 256) {                                  \
        const float4 c = cg[i + ((P) << 10)];                                  \
        float p0 = c.x*c.x, p1 = c.y*c.y, p2 = c.z*c.z, p3 = c.w*c.w;          \
        sn[i] = ((p0 + p1) + p2) + p3;        /* norm of ORIGINAL c */         \
        float4 c2;                                                             \
        c2.x = -2.0f*c.x; c2.y = -2.0f*c.y;                                    \
        c2.z = -2.0f*c.z; c2.w = -2.0f*c.w;   /* exact scaling */              \
        sc[i] = c2;                                                            \
    }

// one candidate's key: dot' = sum cv*(-2cw) == -2*dot bitwise;
// sd = (dot'+nv)+nw matches ref's (-2dot+nv)+nw add order.
#define CAND_KEY(K, slot, T)                                                   \
    {                                                                          \
        const int w  = ((T) << 5) + l;                                         \
        const int wi = w & (VV / 2 - 1);                                       \
        const float4 cw = sc[wi];                                              \
        const float  nw = sn[wi];                                              \
        float q0 = cv.x*cw.x, q1 = cv.y*cw.y,                                  \
              q2 = cv.z*cw.z, q3 = cv.w*cw.w;                                  \
        float dotp = ((q0 + q1) + q2) + q3;                                    \
        float sd = dotp + nv;                                                  \
        sd = sd + nw;                                                          \
        sd = fabsf(sd);                                                        \
        const float dvf = (w < Aieff) ? sd : FLT_MAX;                          \
        K[slot] = mk_key(dvf, (u32)w);                                         \
    }

#define SCAN_BATCH(M)                                                          \
    {                                                                          \
        const int bt = (M) << 4;                                               \
        double bk[16];                                                         \
        _Pragma("unroll")                                                      \
        for (int k = 0; k < 16; ++k) CAND_KEY(bk, k, bt + k)                   \
        SORT8D(bk, 0)                                                          \
        SORT8D(bk, 8)                                                          \
        double s8[KK];                     /* 8 smallest of 16, sorted */      \
        s8[0] = fmin(bk[0], bk[15]); s8[1] = fmin(bk[1], bk[14]);              \
        s8[2] = fmin(bk[2], bk[13]); s8[3] = fmin(bk[3], bk[12]);              \
        s8[4] = fmin(bk[4], bk[11]); s8[5] = fmin(bk[5], bk[10]);              \
        s8[6] = fmin(bk[6], bk[9]);  s8[7] = fmin(bk[7], bk[8]);               \
        CLEAN8D(s8)                                                            \
        MERGE8D(top, s8)                                                       \
    }

    // ---- pass 1: candidates w in [0, 1024) ----
    STAGE(0)
    __syncthreads();
    if (heavy) {
        for (int m = 0; m < nb1; ++m) SCAN_BATCH(m)
    }

    // ---- pass 2: candidates w in [1024, 2048) ----
    if (nb > 2) {
        __syncthreads();          // everyone done reading pass-1 LDS
        STAGE(1)
        __syncthreads();
        if (heavy) {
            for (int m = 2; m < nb; ++m) SCAN_BATCH(m)
        }
    }
#undef STAGE
#undef CAND_KEY
#undef SCAN_BATCH

    // ---- trivial rows: top-8 of all-FLT_MAX row = indices 0..7 ----
    if (!heavy) {
        if (l >= 1 && l < KK)
            out_dist[row * (KK - 1) + (l - 1)] = BF16_SAFE_MAX;
#pragma unroll
        for (int r = 1; r < KK; ++r) {
            const float2 val = reinterpret_cast<const float2*>(
                feats + ((size_t)b * VV + r) * FF)[l];
            reinterpret_cast<float2*>(out_feat + (row * (KK - 1) + (r - 1)) * FF)[l] = val;
        }
        return;
    }

    // ---- 5-level truncated bitonic merge across the 32-lane group ----
#pragma unroll
    for (int step = 1; step < 32; step <<= 1) {
        double t[KK];
#pragma unroll
        for (int i = 0; i < KK; ++i) {
            double pb = shfl_xor_f64(top[KK - 1 - i], step);
            t[i] = fmin(top[i], pb);
        }
        CLEAN8D(t)
#pragma unroll
        for (int i = 0; i < KK; ++i) top[i] = t[i];
    }
    // all 32 lanes hold the row's top-8 ascending; rank 0 = self/dropped

    // ---- epilogue ----
    u32 kd = 0;
#pragma unroll
    for (int r = 1; r < KK; ++r) kd = (l == r) ? key_dist(top[r]) : kd;
    if (l >= 1 && l < KK) {
        float d = __uint_as_float(kd);
        if (!(d <= BF16_SAFE_MAX)) d = BF16_SAFE_MAX;  // finite in bf16; kills NaN
        out_dist[row * (KK - 1) + (l - 1)] = d;
    }

#pragma unroll
    for (int r = 1; r < KK; ++r) {
        const u32 idx = key_idx(top[r]);
        const float2 val = reinterpret_cast<const float2*>(
            feats + ((size_t)b * VV + idx) * FF)[l];
        reinterpret_cast<float2*>(out_feat + (row * (KK - 1) + (r - 1)) * FF)[l] = val;
    }
}

extern "C" void kernel_launch(void* const* d_in, const int* in_sizes, int n_in,
                              void* d_out, int out_size, void* d_ws, size_t ws_size,
                              hipStream_t stream)
{
    const float* coords = (const float*)d_in[0];
    const float* feats  = (const float*)d_in[1];
    const float* act    = (const float*)d_in[2];
    float* out_dist = (float*)d_out;
    float* out_feat = out_dist + (size_t)BB * VV * (KK - 1);

    dim3 grid(VV / 8, BB);    // 2048 blocks, 8 strided rows each
    knn_topk_kernel<<<grid, dim3(256), 0, stream>>>(coords, feats, act,
                                                    out_dist, out_feat);
}